// Round 5
// baseline (6866.737 us; speedup 1.0000x reference)
//
#include <hip/hip_runtime.h>
#include <cstdint>

#define B_  64
#define T_  4096
#define F_  100
#define H_  200
#define G_  600   // 3H
#define KP_ 224   // K (=H) padded to 2 x 112 for 16B-aligned half-slices
#define KH_ 112   // KP_/2 half2 rows in packed Wh

typedef _Float16 half2_t __attribute__((ext_vector_type(2)));

__device__ __forceinline__ float sigmoid_rcp_(float x) {
    return __builtin_amdgcn_rcpf(1.0f + __expf(-x));   // v_rcp: 1ulp, ~4 instr total
}
__device__ __forceinline__ float tanh_rcp_(float x) {
    float e = __expf(-2.0f * x);
    return (1.0f - e) * __builtin_amdgcn_rcpf(1.0f + e);
}

__device__ __forceinline__ float fdot2_(half2_t a, half2_t b, float c) {
#if __has_builtin(__builtin_amdgcn_fdot2)
    return __builtin_amdgcn_fdot2(a, b, c, false);
#else
    return fmaf((float)a.x, (float)b.x, fmaf((float)a.y, (float)b.y, c));
#endif
}

// lane-pair (xor 1) sum via DPP quad_perm [1,0,3,2] — pure VALU.
__device__ __forceinline__ float dpp_xor1_add(float x) {
    int y = __builtin_amdgcn_update_dpp(0, __float_as_int(x), 0xB1, 0xF, 0xF, true);
    return x + __int_as_float(y);
}
// broadcast even lane of each pair to both lanes: quad_perm [0,0,2,2]
__device__ __forceinline__ float dpp_bcast_even(float x) {
    int y = __builtin_amdgcn_update_dpp(0, __float_as_int(x), 0xA0, 0xF, 0xF, true);
    return __int_as_float(y);
}

// ---------------- Phase 0: pack Wh (f32 [200,600]) -> half2 [112][600] ----------------
// whp[k*600 + c] = (Wh[2k][c], Wh[2k+1][c]); rows 100..111 zero (K padded 200->224)
__global__ void prep_whp(const float* __restrict__ Wh, half2_t* __restrict__ whp) {
    int i = blockIdx.x * 256 + threadIdx.x;
    if (i < KH_ * G_) {
        int k = i / G_, c = i - k * G_;
        half2_t v;
        v.x = (k < 100) ? (_Float16)Wh[(2 * k) * G_ + c] : (_Float16)0.f;
        v.y = (k < 100) ? (_Float16)Wh[(2 * k + 1) * G_ + c] : (_Float16)0.f;
        whp[i] = v;
    }
}

// ---------------- Phase 1: gi = x @ Wi + bi (fp32) ----------------
// Session-verified 640-thread structure; GATE-INTERLEAVED store layout
// gi[row*600 + e*3 + gate] (verified r3) for the scan's per-pair prefetch.
__global__ __launch_bounds__(640, 1)
void gi_kernel(const float* __restrict__ x, const float* __restrict__ Wi,
               const float* __restrict__ bi, float* __restrict__ gi,
               int t0, int TC) {
    __shared__ float xT[F_ * 68];
    int row0 = blockIdx.x * 64;
    int b    = row0 / TC;
    int tc0  = row0 - b * TC;
    const float* xrow = x + ((size_t)b * T_ + t0 + tc0) * F_;
    for (int i = threadIdx.x; i < 64 * F_; i += 640) {
        int r = i / F_, f = i - r * F_;
        xT[f * 68 + r] = xrow[i];
    }
    __syncthreads();
    int col = threadIdx.x < G_ ? threadIdx.x : G_ - 1;
    float acc[64];
    #pragma unroll
    for (int r = 0; r < 64; ++r) acc[r] = 0.f;
    for (int f = 0; f < F_; ++f) {
        float wi = Wi[f * G_ + col];
        const float4* xf = (const float4*)&xT[f * 68];
        #pragma unroll
        for (int q = 0; q < 16; ++q) {
            float4 v = xf[q];
            acc[4*q+0] = fmaf(v.x, wi, acc[4*q+0]);
            acc[4*q+1] = fmaf(v.y, wi, acc[4*q+1]);
            acc[4*q+2] = fmaf(v.z, wi, acc[4*q+2]);
            acc[4*q+3] = fmaf(v.w, wi, acc[4*q+3]);
        }
    }
    if (threadIdx.x < G_) {
        int gate = col / H_;
        int e    = col - gate * H_;
        float bv = bi[col];
        float* grow = gi + (size_t)row0 * G_ + (size_t)e * 3 + gate;
        #pragma unroll 4
        for (int r = 0; r < 64; ++r) grow[(size_t)r * G_] = acc[r] + bv;
    }
}

// ---------------- Phase 2: sequential GRU scan ----------------
// 64 blocks (one per batch), 448 threads (7 waves, 2/SIMD -> 256-reg budget).
// Lane pair (2p, 2p+1) owns h-element p; lane s=tid&1 covers K-half
// [112s, 112s+112) of ALL THREE gate columns {p, 200+p, 400+p}.
// Weights: 3 x 56 = 168 half2 regs + ~60 working = ~230 <= 256: no scratch,
// max headroom for arch-VGPR placement (r1-r3 showed arch ~ budget/2 and
// r3's budget-128 straitjacket caused loop scratch spills -> regression).
// Step wall model is ISSUE-bound: 7 waves x ~230 instr x 2cyc / 4 SIMD ~ 800cyc
// vs r3's ~1500. DPP pair-butterfly fuses elementwise in-thread; double-
// buffered h keeps ONE barrier per step (both verified r2/r3).
__global__ __launch_bounds__(448, 2)
void scan_kernel(const float* __restrict__ gi, const half2_t* __restrict__ whp,
                 const float* __restrict__ bhn, _Float16* __restrict__ hs,
                 float* __restrict__ hstate, int TC, int first) {
    __shared__ __align__(16) _Float16 h_h[2][KP_];   // double-buffered h (f16)
    int b = blockIdx.x;
    int tid = threadIdx.x;
    int p = tid >> 1;                 // h-element, [0,224)
    int s = tid & 1;                  // K-half
    int pc = p < H_ ? p : H_ - 1;     // clamp: pairs 200..223 duplicate, never write
    bool writer = (s == 0 && p < H_);

    half2_t wr[56], wz[56], wn[56];   // 168 VGPRs of packed f16 weights
    const half2_t* wbase = whp + (size_t)(56 * s) * G_ + pc;
    #pragma unroll
    for (int j = 0; j < 56; ++j) {
        wr[j] = wbase[(size_t)j * G_];
        wz[j] = wbase[(size_t)j * G_ + H_];
        wn[j] = wbase[(size_t)j * G_ + 2 * H_];
    }
    float bhn_r = (s == 1) ? bhn[pc] : 0.f;   // folded once into n-dot partial

    float hj = first ? 0.f : hstate[b * H_ + pc];   // both lanes track h[p]
    if (writer) h_h[0][p] = (_Float16)hj;
    if (tid < 2 * (KP_ - H_)) {                     // zero K-padding, both buffers
        int buf = tid / (KP_ - H_), e = tid - buf * (KP_ - H_);
        h_h[buf][H_ + e] = (_Float16)0.f;
    }
    __syncthreads();

    const float* girow = gi + (size_t)b * TC * G_;
    _Float16* hsb = hs + (size_t)b * TC * H_;

    int p3 = pc * 3;
    // lane0 carries {gi_r, gi_n}; lane1 carries {gi_z}
    float ga = girow[p3 + (s ? 1 : 0)];
    float gb = s ? 0.f : girow[p3 + 2];
    int cur = 0;
    for (int tc = 0; tc < TC; ++tc) {
        float gan = 0.f, gbn = 0.f;               // prefetch next step
        if (tc + 1 < TC) {
            const float* gnext = girow + (size_t)(tc + 1) * G_ + p3;
            gan = gnext[s ? 1 : 0];
            if (!s) gbn = gnext[2];
        }
        // K-half partial dots; h broadcast from LDS (14 x b128, each reused x3)
        float r0 = 0.f, r1 = 0.f, z0 = 0.f, z1 = 0.f, n0 = 0.f, n1 = 0.f;
        const float4* h4 = (const float4*)(&h_h[cur][0]) + 14 * s;
        #pragma unroll
        for (int q = 0; q < 14; ++q) {
            float4 hv = h4[q];
            half2_t* hp = (half2_t*)&hv;
            r0 = fdot2_(hp[0], wr[4*q+0], r0);
            z0 = fdot2_(hp[0], wz[4*q+0], z0);
            n0 = fdot2_(hp[0], wn[4*q+0], n0);
            r1 = fdot2_(hp[1], wr[4*q+1], r1);
            z1 = fdot2_(hp[1], wz[4*q+1], z1);
            n1 = fdot2_(hp[1], wn[4*q+1], n1);
            r0 = fdot2_(hp[2], wr[4*q+2], r0);
            z0 = fdot2_(hp[2], wz[4*q+2], z0);
            n0 = fdot2_(hp[2], wn[4*q+2], n0);
            r1 = fdot2_(hp[3], wr[4*q+3], r1);
            z1 = fdot2_(hp[3], wz[4*q+3], z1);
            n1 = fdot2_(hp[3], wn[4*q+3], n1);
        }
        float pr = r0 + r1, pz = z0 + z1, pn = n0 + n1;
        pr += s ? 0.f : ga;           // fold gi_r once (lane0)
        pz += s ? ga : 0.f;           // fold gi_z once (lane1)
        pn += bhn_r;                  // fold bhn once (lane1); INSIDE r*(...) term
        // pair butterfly: both lanes get full R, Z, N for their h-element
        float R = dpp_xor1_add(pr);
        float Z = dpp_xor1_add(pz);
        float N = dpp_xor1_add(pn);
        float gn = dpp_bcast_even(gb);   // gi_n from lane0 (OUTSIDE r*(...))
        float rr = sigmoid_rcp_(R);
        float zz = sigmoid_rcp_(Z);
        float nn = tanh_rcp_(gn + rr * N);
        hj = nn + zz * (hj - nn);     // both lanes redundantly
        if (writer) {
            h_h[cur ^ 1][p] = (_Float16)hj;
            hsb[(size_t)tc * H_ + p] = (_Float16)hj;   // fire-and-forget
        }
        __syncthreads();              // ONE barrier per step (double-buffered h)
        ga = gan; gb = gbn;
        cur ^= 1;
    }
    if (writer) hstate[b * H_ + p] = hj;
}

// ---------------- Phase 3: out = hs @ Wo + bo ----------------
__global__ __launch_bounds__(256, 4)
void outproj_kernel(const _Float16* __restrict__ hs, const float* __restrict__ Wo,
                    const float* __restrict__ bo, float* __restrict__ out,
                    int t0, int TC) {
    int r = blockIdx.x * 256 + threadIdx.x;
    if (r >= B_ * TC) return;
    int b = r / TC, tc = r - b * TC;
    const float4* h4 = (const float4*)(hs + (size_t)r * H_);
    float acc = 0.f;
    #pragma unroll
    for (int q = 0; q < 25; ++q) {
        float4 v = h4[q];
        const _Float16* hp = (const _Float16*)&v;
        #pragma unroll
        for (int j = 0; j < 8; ++j)
            acc = fmaf((float)hp[j], Wo[q * 8 + j], acc);
    }
    out[(size_t)b * T_ + t0 + tc] = acc + bo[0];
}

extern "C" void kernel_launch(void* const* d_in, const int* in_sizes, int n_in,
                              void* d_out, int out_size, void* d_ws, size_t ws_size,
                              hipStream_t stream) {
    const float* x   = (const float*)d_in[0];
    const float* Wi  = (const float*)d_in[1];
    const float* bi  = (const float*)d_in[2];
    const float* Wh  = (const float*)d_in[3];
    const float* bhn = (const float*)d_in[4];
    const float* Wo  = (const float*)d_in[5];
    const float* bo  = (const float*)d_in[6];
    float* out = (float*)d_out;

    const size_t hstate_b = (size_t)B_ * H_ * sizeof(float);
    const size_t whp_b    = (size_t)KH_ * G_ * sizeof(half2_t);
    // ws layout: [gi: B*TC*G*4][hs: B*TC*H*2][hstate][whp]
    int TC = T_;
    while (TC > 64 &&
           (size_t)B_ * TC * (G_ * 4 + H_ * 2) + hstate_b + whp_b > ws_size)
        TC >>= 1;
    char* p = (char*)d_ws;
    float*    gi     = (float*)p;            p += (size_t)B_ * TC * G_ * sizeof(float);
    _Float16* hsbuf  = (_Float16*)p;         p += (size_t)B_ * TC * H_ * sizeof(_Float16);
    float*    hstate = (float*)p;            p += hstate_b;
    half2_t*  whp    = (half2_t*)p;

    prep_whp<<<dim3((KH_ * G_ + 255) / 256), dim3(256), 0, stream>>>(Wh, whp);

    int nchunks = T_ / TC;
    for (int c = 0; c < nchunks; ++c) {
        int t0 = c * TC;
        gi_kernel<<<dim3(B_ * TC / 64), dim3(640), 0, stream>>>(x, Wi, bi, gi, t0, TC);
        scan_kernel<<<dim3(B_), dim3(448), 0, stream>>>(gi, whp, bhn, hsbuf,
                                                        hstate, TC, c == 0);
        outproj_kernel<<<dim3((B_ * TC + 255) / 256), dim3(256), 0, stream>>>(
            hsbuf, Wo, bo, out, t0, TC);
    }
}

// Round 6
// 5402.577 us; speedup vs baseline: 1.2710x; 1.2710x over previous
//
#include <hip/hip_runtime.h>
#include <cstdint>

#define B_  64
#define T_  4096
#define F_  100
#define H_  200
#define G_  600   // 3H
#define KH_ 104   // padded half2 rows of Wh (K 200 -> 208)

typedef _Float16 half2_t __attribute__((ext_vector_type(2)));

// LDS-only workgroup barrier. __syncthreads() emits s_waitcnt vmcnt(0)
// lgkmcnt(0) before s_barrier, draining the fire-and-forget hsb global store
// (~300+cy ack) and the g prefetch loads (~200cy L2) into the serial per-step
// chain TWICE per step. The in-loop barriers only need LDS visibility ->
// wait lgkmcnt only. sched_barrier(0) fences keep LDS ops from crossing
// (guide rule #18); the compiler still auto-inserts vmcnt(N) before g use.
#define LDS_BARRIER() do {                                  \
    __builtin_amdgcn_sched_barrier(0);                      \
    asm volatile("s_waitcnt lgkmcnt(0)" ::: "memory");      \
    __builtin_amdgcn_s_barrier();                           \
    __builtin_amdgcn_sched_barrier(0);                      \
} while (0)

__device__ __forceinline__ float sigmoid_(float x) {
    return __builtin_amdgcn_rcpf(1.0f + __expf(-x));   // precision-validated r5
}
__device__ __forceinline__ float tanh_(float x) {
    float e = __expf(-2.0f * x);
    return (1.0f - e) * __builtin_amdgcn_rcpf(1.0f + e);
}

__device__ __forceinline__ float fdot2_(half2_t a, half2_t b, float c) {
#if __has_builtin(__builtin_amdgcn_fdot2)
    return __builtin_amdgcn_fdot2(a, b, c, false);
#else
    return fmaf((float)a.x, (float)b.x, fmaf((float)a.y, (float)b.y, c));
#endif
}

// lane-pair (xor 1) sum via DPP quad_perm [1,0,3,2] — pure VALU, no LDS pipe.
__device__ __forceinline__ float dpp_xor1_add(float x) {
    int y = __builtin_amdgcn_update_dpp(0, __float_as_int(x), 0xB1, 0xF, 0xF, true);
    return x + __int_as_float(y);
}

// ---------------- Phase 0: pack Wh (f32 [200,600]) -> half2 [104][600] ----------------
// whp[k*600 + c] = (Wh[2k][c], Wh[2k+1][c]); rows 100..103 zero (K padded 200->208)
__global__ void prep_whp(const float* __restrict__ Wh, half2_t* __restrict__ whp) {
    int i = blockIdx.x * 256 + threadIdx.x;
    if (i < KH_ * G_) {
        int k = i / G_, c = i - k * G_;
        half2_t v;
        v.x = (k < 100) ? (_Float16)Wh[(2 * k) * G_ + c] : (_Float16)0.f;
        v.y = (k < 100) ? (_Float16)Wh[(2 * k + 1) * G_ + c] : (_Float16)0.f;
        whp[i] = v;
    }
}

// ---------------- Phase 1: gi = x @ Wi + bi (fp32) ----------------
// (session-verified 640-thread version, plain gi[row*600+col] layout)
__global__ __launch_bounds__(640, 1)
void gi_kernel(const float* __restrict__ x, const float* __restrict__ Wi,
               const float* __restrict__ bi, float* __restrict__ gi,
               int t0, int TC) {
    __shared__ float xT[F_ * 68];
    int row0 = blockIdx.x * 64;
    int b    = row0 / TC;
    int tc0  = row0 - b * TC;
    const float* xrow = x + ((size_t)b * T_ + t0 + tc0) * F_;
    for (int i = threadIdx.x; i < 64 * F_; i += 640) {
        int r = i / F_, f = i - r * F_;
        xT[f * 68 + r] = xrow[i];
    }
    __syncthreads();
    int col = threadIdx.x < G_ ? threadIdx.x : G_ - 1;
    float acc[64];
    #pragma unroll
    for (int r = 0; r < 64; ++r) acc[r] = 0.f;
    for (int f = 0; f < F_; ++f) {
        float wi = Wi[f * G_ + col];
        const float4* xf = (const float4*)&xT[f * 68];
        #pragma unroll
        for (int q = 0; q < 16; ++q) {
            float4 v = xf[q];
            acc[4*q+0] = fmaf(v.x, wi, acc[4*q+0]);
            acc[4*q+1] = fmaf(v.y, wi, acc[4*q+1]);
            acc[4*q+2] = fmaf(v.z, wi, acc[4*q+2]);
            acc[4*q+3] = fmaf(v.w, wi, acc[4*q+3]);
        }
    }
    if (threadIdx.x < G_) {
        float bv = bi[col];
        float* grow = gi + (size_t)row0 * G_ + col;
        #pragma unroll 4
        for (int r = 0; r < 64; ++r) grow[(size_t)r * G_] = acc[r] + bv;
    }
}

// ---------------- Phase 2: sequential GRU scan ----------------
// Champion structure (2210us/chunk measured): 64 blocks, 640 threads (10 waves).
// Lane pair (2p, 2p+1) owns columns {p, p+300}; lane s=tid&1 covers K-half
// [104s, 104s+104). Weights: 2 cols x 52 half2 = 104 regs/thread.
// Cost model (fits r1/r2/r5 counters): v_dot2_f32_f16 issues at ~4cyc/wave ->
// dot issue = 2.5 waves/SIMD x 104 x 4 ~ 1040 cyc/step, already at the chip
// floor (~937). The change this round: LDS-only barriers remove the per-step
// vmcnt(0) drain of the hsb store + g loads from the serial chain.
__global__ __launch_bounds__(640, 1)
void scan_kernel(const float* __restrict__ gi, const half2_t* __restrict__ whp,
                 const float* __restrict__ bhn, _Float16* __restrict__ hs,
                 float* __restrict__ hstate, int TC, int first) {
    __shared__ __align__(16) _Float16 h_h[208];   // h in f16, padded 200->208 with zeros
    __shared__ float A_lds[G_];
    __shared__ float Hn_lds[H_];
    int b = blockIdx.x;
    int tid = threadIdx.x;
    int p = tid >> 1;                 // pair id, [0,320)
    int s = tid & 1;                  // K-half
    if (p >= 300) p = 299;            // clamp: threads 600..639 duplicate, benign
    int c0 = p;
    int c1 = p + 300;

    half2_t wa[52], wb[52];           // 104 regs of packed f16 weights
    #pragma unroll
    for (int j = 0; j < 52; ++j) {
        wa[j] = whp[(52 * s + j) * G_ + c0];
        wb[j] = whp[(52 * s + j) * G_ + c1];
    }
    float bhn_r = (c1 >= 2*H_) ? bhn[c1 - 2*H_] : 0.f;

    float hj = 0.f;
    if (tid < H_) {
        hj = first ? 0.f : hstate[b * H_ + tid];
        h_h[tid] = (_Float16)hj;
    }
    if (tid >= H_ && tid < 208) h_h[tid] = (_Float16)0.f;
    __syncthreads();

    const float* girow = gi + (size_t)b * TC * G_;
    _Float16* hsb = hs + (size_t)b * TC * H_;

    float g0 = 0.f, g1 = 0.f;
    if (s == 0) { g0 = girow[c0]; g1 = girow[c1]; }       // prefetch step 0
    for (int tc = 0; tc < TC; ++tc) {
        float g0n = 0.f, g1n = 0.f;                       // prefetch next step
        if (s == 0 && tc + 1 < TC) {
            g0n = girow[(size_t)(tc + 1) * G_ + c0];
            g1n = girow[(size_t)(tc + 1) * G_ + c1];
        }
        // partial dots over this lane's K-half; h broadcast from LDS as f16 float4
        float a0 = 0.f, a1 = 0.f, a2 = 0.f, a3 = 0.f;
        float b0 = 0.f, b1 = 0.f, b2 = 0.f, b3 = 0.f;
        const float4* h4 = (const float4*)(h_h + 104 * s);   // 16B-aligned
        #pragma unroll
        for (int q = 0; q < 13; ++q) {
            float4 hv = h4[q];                   // 8 halves = 4 half2
            half2_t* hp = (half2_t*)&hv;
            a0 = fdot2_(hp[0], wa[4*q+0], a0);
            a1 = fdot2_(hp[1], wa[4*q+1], a1);
            a2 = fdot2_(hp[2], wa[4*q+2], a2);
            a3 = fdot2_(hp[3], wa[4*q+3], a3);
            b0 = fdot2_(hp[0], wb[4*q+0], b0);
            b1 = fdot2_(hp[1], wb[4*q+1], b1);
            b2 = fdot2_(hp[2], wb[4*q+2], b2);
            b3 = fdot2_(hp[3], wb[4*q+3], b3);
        }
        float accA = dpp_xor1_add((a0 + a1) + (a2 + a3));   // sum across lane pair
        float accB = dpp_xor1_add((b0 + b1) + (b2 + b3));
        if (s == 0) {
            A_lds[c0] = g0 + accA;               // c0 in [0,300): r or z cols
            if (c1 < 2*H_) {
                A_lds[c1] = g1 + accB;           // z cols 300..399
            } else {
                A_lds[c1] = g1;                  // n cols 400..599
                Hn_lds[c1 - 2*H_] = accB + bhn_r;
            }
        }
        LDS_BARRIER();                // LDS-visibility only: VMEM stays in flight
        if (tid < H_) {
            float r = sigmoid_(A_lds[tid]);
            float z = sigmoid_(A_lds[H_ + tid]);
            float n = tanh_(A_lds[2*H_ + tid] + r * Hn_lds[tid]);
            hj = n + z * (hj - n);
            h_h[tid] = (_Float16)hj;
            hsb[(size_t)tc * H_ + tid] = (_Float16)hj;   // truly fire-and-forget now
        }
        LDS_BARRIER();
        g0 = g0n; g1 = g1n;
    }
    if (tid < H_) hstate[b * H_ + tid] = hj;
}

// ---------------- Phase 3: out = hs @ Wo + bo ----------------
__global__ __launch_bounds__(256, 4)
void outproj_kernel(const _Float16* __restrict__ hs, const float* __restrict__ Wo,
                    const float* __restrict__ bo, float* __restrict__ out,
                    int t0, int TC) {
    int r = blockIdx.x * 256 + threadIdx.x;
    if (r >= B_ * TC) return;
    int b = r / TC, tc = r - b * TC;
    const float4* h4 = (const float4*)(hs + (size_t)r * H_);
    float acc = 0.f;
    #pragma unroll
    for (int q = 0; q < 25; ++q) {
        float4 v = h4[q];
        const _Float16* hp = (const _Float16*)&v;
        #pragma unroll
        for (int j = 0; j < 8; ++j)
            acc = fmaf((float)hp[j], Wo[q * 8 + j], acc);
    }
    out[(size_t)b * T_ + t0 + tc] = acc + bo[0];
}

extern "C" void kernel_launch(void* const* d_in, const int* in_sizes, int n_in,
                              void* d_out, int out_size, void* d_ws, size_t ws_size,
                              hipStream_t stream) {
    const float* x   = (const float*)d_in[0];
    const float* Wi  = (const float*)d_in[1];
    const float* bi  = (const float*)d_in[2];
    const float* Wh  = (const float*)d_in[3];
    const float* bhn = (const float*)d_in[4];
    const float* Wo  = (const float*)d_in[5];
    const float* bo  = (const float*)d_in[6];
    float* out = (float*)d_out;

    const size_t hstate_b = (size_t)B_ * H_ * sizeof(float);
    const size_t whp_b    = (size_t)KH_ * G_ * sizeof(half2_t);
    // ws layout: [gi: B*TC*G*4][hs: B*TC*H*2][hstate][whp]
    int TC = T_;
    while (TC > 64 &&
           (size_t)B_ * TC * (G_ * 4 + H_ * 2) + hstate_b + whp_b > ws_size)
        TC >>= 1;
    char* p = (char*)d_ws;
    float*    gi     = (float*)p;            p += (size_t)B_ * TC * G_ * sizeof(float);
    _Float16* hsbuf  = (_Float16*)p;         p += (size_t)B_ * TC * H_ * sizeof(_Float16);
    float*    hstate = (float*)p;            p += hstate_b;
    half2_t*  whp    = (half2_t*)p;

    prep_whp<<<dim3((KH_ * G_ + 255) / 256), dim3(256), 0, stream>>>(Wh, whp);

    int nchunks = T_ / TC;
    for (int c = 0; c < nchunks; ++c) {
        int t0 = c * TC;
        gi_kernel<<<dim3(B_ * TC / 64), dim3(640), 0, stream>>>(x, Wi, bi, gi, t0, TC);
        scan_kernel<<<dim3(B_), dim3(640), 0, stream>>>(gi, whp, bhn, hsbuf,
                                                        hstate, TC, c == 0);
        outproj_kernel<<<dim3((B_ * TC + 255) / 256), dim3(256), 0, stream>>>(
            hsbuf, Wo, bo, out, t0, TC);
    }
}

// Round 7
// 5398.308 us; speedup vs baseline: 1.2720x; 1.0008x over previous
//
#include <hip/hip_runtime.h>
#include <cstdint>

#define B_  64
#define T_  4096
#define F_  100
#define H_  200
#define G_  600   // 3H
#define KP_ 224   // K (=H) padded to 4 x 56 for 16B-aligned quarter-slices
#define KH_ 112   // KP_/2 half2 rows in packed Wh

typedef _Float16 half2_t __attribute__((ext_vector_type(2)));

// LDS-only workgroup barrier (verified r6: removes per-step vmcnt(0) drain).
#define LDS_BARRIER() do {                                  \
    __builtin_amdgcn_sched_barrier(0);                      \
    asm volatile("s_waitcnt lgkmcnt(0)" ::: "memory");      \
    __builtin_amdgcn_s_barrier();                           \
    __builtin_amdgcn_sched_barrier(0);                      \
} while (0)

__device__ __forceinline__ float sigmoid_(float x) {
    return __builtin_amdgcn_rcpf(1.0f + __expf(-x));   // precision-validated r5/r6
}
__device__ __forceinline__ float tanh_(float x) {
    float e = __expf(-2.0f * x);
    return (1.0f - e) * __builtin_amdgcn_rcpf(1.0f + e);
}

__device__ __forceinline__ float fdot2_(half2_t a, half2_t b, float c) {
#if __has_builtin(__builtin_amdgcn_fdot2)
    return __builtin_amdgcn_fdot2(a, b, c, false);
#else
    return fmaf((float)a.x, (float)b.x, fmaf((float)a.y, (float)b.y, c));
#endif
}

// full quad (4-lane) butterfly sum via DPP quad_perm — pure VALU, no LDS pipe.
__device__ __forceinline__ float quad_sum_(float x) {
    int y1 = __builtin_amdgcn_update_dpp(0, __float_as_int(x), 0xB1, 0xF, 0xF, true); // [1,0,3,2]
    x += __int_as_float(y1);
    int y2 = __builtin_amdgcn_update_dpp(0, __float_as_int(x), 0x4E, 0xF, 0xF, true); // [2,3,0,1]
    return x + __int_as_float(y2);
}

// ---------------- Phase 0: pack Wh (f32 [200,600]) -> half2 [112][600] ----------------
// whp[k*600 + c] = (Wh[2k][c], Wh[2k+1][c]); rows 100..111 zero (K padded 200->224)
__global__ void prep_whp(const float* __restrict__ Wh, half2_t* __restrict__ whp) {
    int i = blockIdx.x * 256 + threadIdx.x;
    if (i < KH_ * G_) {
        int k = i / G_, c = i - k * G_;
        half2_t v;
        v.x = (k < 100) ? (_Float16)Wh[(2 * k) * G_ + c] : (_Float16)0.f;
        v.y = (k < 100) ? (_Float16)Wh[(2 * k + 1) * G_ + c] : (_Float16)0.f;
        whp[i] = v;
    }
}

// ---------------- Phase 1: gi = x @ Wi + bi (fp32) ----------------
// (session-verified 640-thread version, plain gi[row*600+col] layout)
__global__ __launch_bounds__(640, 1)
void gi_kernel(const float* __restrict__ x, const float* __restrict__ Wi,
               const float* __restrict__ bi, float* __restrict__ gi,
               int t0, int TC) {
    __shared__ float xT[F_ * 68];
    int row0 = blockIdx.x * 64;
    int b    = row0 / TC;
    int tc0  = row0 - b * TC;
    const float* xrow = x + ((size_t)b * T_ + t0 + tc0) * F_;
    for (int i = threadIdx.x; i < 64 * F_; i += 640) {
        int r = i / F_, f = i - r * F_;
        xT[f * 68 + r] = xrow[i];
    }
    __syncthreads();
    int col = threadIdx.x < G_ ? threadIdx.x : G_ - 1;
    float acc[64];
    #pragma unroll
    for (int r = 0; r < 64; ++r) acc[r] = 0.f;
    for (int f = 0; f < F_; ++f) {
        float wi = Wi[f * G_ + col];
        const float4* xf = (const float4*)&xT[f * 68];
        #pragma unroll
        for (int q = 0; q < 16; ++q) {
            float4 v = xf[q];
            acc[4*q+0] = fmaf(v.x, wi, acc[4*q+0]);
            acc[4*q+1] = fmaf(v.y, wi, acc[4*q+1]);
            acc[4*q+2] = fmaf(v.z, wi, acc[4*q+2]);
            acc[4*q+3] = fmaf(v.w, wi, acc[4*q+3]);
        }
    }
    if (threadIdx.x < G_) {
        float bv = bi[col];
        float* grow = gi + (size_t)row0 * G_ + col;
        #pragma unroll 4
        for (int r = 0; r < 64; ++r) grow[(size_t)r * G_] = acc[r] + bv;
    }
}

// ---------------- Phase 2: sequential GRU scan ----------------
// 64 blocks (one per batch), 512 threads (8 waves = EXACTLY 2/EU).
// amdgpu_waves_per_eu(2,2) pins the occupancy target so the allocator gets a
// FULL 256-reg arch budget (r1-r5 showed launch_bounds' min-waves arg alone
// lets the compiler target higher occupancy and split big arrays into AGPRs:
// VGPR_Count was always ~half the weight count; each use then pays a move —
// the measured 2.3x VALU inflation vs hand count).
// Quad 4q..4q+3 owns cols [5q, 5q+5); lane l=tid&3 covers K-quarter
// [56l, 56l+56) of all 5 cols. Weights: 5 x 28 = 140 half2 regs + ~60 working
// = ~200 <= 256 -> no pressure, no split possible.
// LDS h-broadcast: 7 ds_read_b128/thread x 8 waves = 56 wave-instrs/step
// (vs 130 in r6 champion), each 16B chunk reused x5. Quad DPP butterfly gives
// every lane all 5 totals; champion A_lds/elementwise flow kept verbatim.
__global__ __launch_bounds__(512, 1) __attribute__((amdgpu_waves_per_eu(2, 2)))
void scan_kernel(const float* __restrict__ gi, const half2_t* __restrict__ whp,
                 const float* __restrict__ bhn, _Float16* __restrict__ hs,
                 float* __restrict__ hstate, int TC, int first) {
    __shared__ __align__(16) _Float16 h_h[KP_];   // h in f16, padded 200->224 with zeros
    __shared__ float A_lds[G_];
    __shared__ float Hn_lds[H_];
    int b = blockIdx.x;
    int tid = threadIdx.x;
    int q = tid >> 2;                 // quad id, [0,128)
    int l = tid & 3;                  // K-quarter
    int qc = q < 120 ? q : 119;       // clamp: quads 120..127 duplicate, never write
    bool act = q < 120;
    int c0 = 5 * qc;                  // quad's first col

    half2_t w[5][28];                 // 140 arch VGPRs of packed f16 weights
    {
        const half2_t* wbase = whp + (size_t)(28 * l) * G_ + c0;
        #pragma unroll
        for (int k = 0; k < 28; ++k) {
            #pragma unroll
            for (int j = 0; j < 5; ++j)
                w[j][k] = wbase[(size_t)k * G_ + j];
        }
    }
    int ca = c0 + l;                  // this lane's col (l in 0..3)
    int cb = c0 + 4;                  // lane0's extra col
    float bhn_a = (ca >= 2*H_) ? bhn[ca - 2*H_] : 0.f;
    float bhn_b = (l == 0 && cb >= 2*H_) ? bhn[cb - 2*H_] : 0.f;

    float hj = 0.f;
    if (tid < H_) {
        hj = first ? 0.f : hstate[b * H_ + tid];
        h_h[tid] = (_Float16)hj;
    }
    if (tid >= H_ && tid < KP_) h_h[tid] = (_Float16)0.f;
    __syncthreads();

    const float* girow = gi + (size_t)b * TC * G_;
    _Float16* hsb = hs + (size_t)b * TC * H_;

    float ga = girow[ca];                         // prefetch step 0
    float gb = (l == 0) ? girow[cb] : 0.f;
    for (int tc = 0; tc < TC; ++tc) {
        float gan = 0.f, gbn = 0.f;               // prefetch next step
        if (tc + 1 < TC) {
            const float* gnx = girow + (size_t)(tc + 1) * G_;
            gan = gnx[ca];
            if (l == 0) gbn = gnx[cb];
        }
        // K-quarter partial dots for 5 cols; h broadcast from LDS (7 x b128, reused x5)
        float pd0[5], pd1[5];
        #pragma unroll
        for (int j = 0; j < 5; ++j) { pd0[j] = 0.f; pd1[j] = 0.f; }
        const float4* h4 = (const float4*)(h_h + 56 * l);   // 112B offset, 16B-aligned
        #pragma unroll
        for (int k4 = 0; k4 < 7; ++k4) {
            float4 hv = h4[k4];                   // 8 halves = 4 half2
            half2_t* hp = (half2_t*)&hv;
            #pragma unroll
            for (int j = 0; j < 5; ++j) {
                pd0[j] = fdot2_(hp[0], w[j][4*k4+0], pd0[j]);
                pd1[j] = fdot2_(hp[1], w[j][4*k4+1], pd1[j]);
                pd0[j] = fdot2_(hp[2], w[j][4*k4+2], pd0[j]);
                pd1[j] = fdot2_(hp[3], w[j][4*k4+3], pd1[j]);
            }
        }
        float tot[5];
        #pragma unroll
        for (int j = 0; j < 5; ++j) tot[j] = quad_sum_(pd0[j] + pd1[j]);
        if (act) {
            // lane l writes its col; cols of a quad never straddle the 2H boundary
            if (ca < 2*H_) {
                A_lds[ca] = ga + tot[l];
            } else {
                A_lds[ca] = ga;
                Hn_lds[ca - 2*H_] = tot[l] + bhn_a;
            }
            if (l == 0) {
                if (cb < 2*H_) {
                    A_lds[cb] = gb + tot[4];
                } else {
                    A_lds[cb] = gb;
                    Hn_lds[cb - 2*H_] = tot[4] + bhn_b;
                }
            }
        }
        LDS_BARRIER();                // LDS-visibility only: VMEM stays in flight
        if (tid < H_) {
            float r = sigmoid_(A_lds[tid]);
            float z = sigmoid_(A_lds[H_ + tid]);
            float n = tanh_(A_lds[2*H_ + tid] + r * Hn_lds[tid]);
            hj = n + z * (hj - n);
            h_h[tid] = (_Float16)hj;
            hsb[(size_t)tc * H_ + tid] = (_Float16)hj;   // fire-and-forget
        }
        LDS_BARRIER();
        ga = gan; gb = gbn;
    }
    if (tid < H_) hstate[b * H_ + tid] = hj;
}

// ---------------- Phase 3: out = hs @ Wo + bo ----------------
__global__ __launch_bounds__(256, 4)
void outproj_kernel(const _Float16* __restrict__ hs, const float* __restrict__ Wo,
                    const float* __restrict__ bo, float* __restrict__ out,
                    int t0, int TC) {
    int r = blockIdx.x * 256 + threadIdx.x;
    if (r >= B_ * TC) return;
    int b = r / TC, tc = r - b * TC;
    const float4* h4 = (const float4*)(hs + (size_t)r * H_);
    float acc = 0.f;
    #pragma unroll
    for (int q = 0; q < 25; ++q) {
        float4 v = h4[q];
        const _Float16* hp = (const _Float16*)&v;
        #pragma unroll
        for (int j = 0; j < 8; ++j)
            acc = fmaf((float)hp[j], Wo[q * 8 + j], acc);
    }
    out[(size_t)b * T_ + t0 + tc] = acc + bo[0];
}

extern "C" void kernel_launch(void* const* d_in, const int* in_sizes, int n_in,
                              void* d_out, int out_size, void* d_ws, size_t ws_size,
                              hipStream_t stream) {
    const float* x   = (const float*)d_in[0];
    const float* Wi  = (const float*)d_in[1];
    const float* bi  = (const float*)d_in[2];
    const float* Wh  = (const float*)d_in[3];
    const float* bhn = (const float*)d_in[4];
    const float* Wo  = (const float*)d_in[5];
    const float* bo  = (const float*)d_in[6];
    float* out = (float*)d_out;

    const size_t hstate_b = (size_t)B_ * H_ * sizeof(float);
    const size_t whp_b    = (size_t)KH_ * G_ * sizeof(half2_t);
    // ws layout: [gi: B*TC*G*4][hs: B*TC*H*2][hstate][whp]
    int TC = T_;
    while (TC > 64 &&
           (size_t)B_ * TC * (G_ * 4 + H_ * 2) + hstate_b + whp_b > ws_size)
        TC >>= 1;
    char* p = (char*)d_ws;
    float*    gi     = (float*)p;            p += (size_t)B_ * TC * G_ * sizeof(float);
    _Float16* hsbuf  = (_Float16*)p;         p += (size_t)B_ * TC * H_ * sizeof(_Float16);
    float*    hstate = (float*)p;            p += hstate_b;
    half2_t*  whp    = (half2_t*)p;

    prep_whp<<<dim3((KH_ * G_ + 255) / 256), dim3(256), 0, stream>>>(Wh, whp);

    int nchunks = T_ / TC;
    for (int c = 0; c < nchunks; ++c) {
        int t0 = c * TC;
        gi_kernel<<<dim3(B_ * TC / 64), dim3(640), 0, stream>>>(x, Wi, bi, gi, t0, TC);
        scan_kernel<<<dim3(B_), dim3(512), 0, stream>>>(gi, whp, bhn, hsbuf,
                                                        hstate, TC, c == 0);
        outproj_kernel<<<dim3((B_ * TC + 255) / 256), dim3(256), 0, stream>>>(
            hsbuf, Wo, bo, out, t0, TC);
    }
}

// Round 8
// 4664.286 us; speedup vs baseline: 1.4722x; 1.1574x over previous
//
#include <hip/hip_runtime.h>
#include <cstdint>

#define B_  64
#define T_  4096
#define F_  100
#define H_  200
#define G_  600   // 3H
#define KH_ 104   // padded half2 rows of Wh (K 200 -> 208)
#define SMEM_PAD 86016   // 84KB/block: 2x84KB>160KB => no block co-residency on a CU

typedef _Float16 half2_t __attribute__((ext_vector_type(2)));

// LDS-only workgroup barrier (verified r6: removes per-step vmcnt(0) drain).
#define LDS_BARRIER() do {                                  \
    __builtin_amdgcn_sched_barrier(0);                      \
    asm volatile("s_waitcnt lgkmcnt(0)" ::: "memory");      \
    __builtin_amdgcn_s_barrier();                           \
    __builtin_amdgcn_sched_barrier(0);                      \
} while (0)

__device__ __forceinline__ float sigmoid_(float x) {
    return __builtin_amdgcn_rcpf(1.0f + __expf(-x));   // precision-validated r5/r6
}
__device__ __forceinline__ float tanh_(float x) {
    float e = __expf(-2.0f * x);
    return (1.0f - e) * __builtin_amdgcn_rcpf(1.0f + e);
}

__device__ __forceinline__ float fdot2_(half2_t a, half2_t b, float c) {
#if __has_builtin(__builtin_amdgcn_fdot2)
    return __builtin_amdgcn_fdot2(a, b, c, false);
#else
    return fmaf((float)a.x, (float)b.x, fmaf((float)a.y, (float)b.y, c));
#endif
}

// lane-pair (xor 1) sum via DPP quad_perm [1,0,3,2] — pure VALU, no LDS pipe.
__device__ __forceinline__ float dpp_xor1_add(float x) {
    int y = __builtin_amdgcn_update_dpp(0, __float_as_int(x), 0xB1, 0xF, 0xF, true);
    return x + __int_as_float(y);
}

// ---------------- Phase 0: pack Wh (f32 [200,600]) -> half2 [104][600] ----------------
__global__ void prep_whp(const float* __restrict__ Wh, half2_t* __restrict__ whp) {
    int i = blockIdx.x * 256 + threadIdx.x;
    if (i < KH_ * G_) {
        int k = i / G_, c = i - k * G_;
        half2_t v;
        v.x = (k < 100) ? (_Float16)Wh[(2 * k) * G_ + c] : (_Float16)0.f;
        v.y = (k < 100) ? (_Float16)Wh[(2 * k + 1) * G_ + c] : (_Float16)0.f;
        whp[i] = v;
    }
}

// ---------------- gi body: gi = x @ Wi + bi (session-verified structure) ----------------
__device__ __forceinline__
void gi_body(char* smem, const float* __restrict__ x, const float* __restrict__ Wi,
             const float* __restrict__ bi, float* __restrict__ gi,
             int t0, int TC, int blk) {
    float* xT = (float*)smem;                       // F_*68 floats = 27.2KB
    int tid = threadIdx.x;
    int row0 = blk * 64;
    int b    = row0 / TC;
    int tc0  = row0 - b * TC;
    const float* xrow = x + ((size_t)b * T_ + t0 + tc0) * F_;
    for (int i = tid; i < 64 * F_; i += 640) {
        int r = i / F_, f = i - r * F_;
        xT[f * 68 + r] = xrow[i];
    }
    __syncthreads();
    int col = tid < G_ ? tid : G_ - 1;
    float acc[64];
    #pragma unroll
    for (int r = 0; r < 64; ++r) acc[r] = 0.f;
    for (int f = 0; f < F_; ++f) {
        float wi = Wi[f * G_ + col];
        const float4* xf = (const float4*)&xT[f * 68];
        #pragma unroll
        for (int q = 0; q < 16; ++q) {
            float4 v = xf[q];
            acc[4*q+0] = fmaf(v.x, wi, acc[4*q+0]);
            acc[4*q+1] = fmaf(v.y, wi, acc[4*q+1]);
            acc[4*q+2] = fmaf(v.z, wi, acc[4*q+2]);
            acc[4*q+3] = fmaf(v.w, wi, acc[4*q+3]);
        }
    }
    if (tid < G_) {
        float bv = bi[col];
        float* grow = gi + (size_t)row0 * G_ + col;
        #pragma unroll 4
        for (int r = 0; r < 64; ++r) grow[(size_t)r * G_] = acc[r] + bv;
    }
}

// ---------------- scan body: r6 champion, verbatim ----------------
__device__ __forceinline__
void scan_body(char* smem, const float* __restrict__ gi, const half2_t* __restrict__ whp,
               const float* __restrict__ bhn, _Float16* __restrict__ hs,
               float* __restrict__ hstate, int TC, int first, int b) {
    _Float16* h_h  = (_Float16*)smem;               // 208 f16 = 416B (pad to 448)
    float*    A_lds = (float*)(smem + 448);         // 600 f32 = 2400B
    float*    Hn_lds = (float*)(smem + 2848);       // 200 f32 = 800B
    int tid = threadIdx.x;
    int p = tid >> 1;                 // pair id, [0,320)
    int s = tid & 1;                  // K-half
    if (p >= 300) p = 299;            // clamp: threads 600..639 duplicate, benign
    int c0 = p;
    int c1 = p + 300;

    half2_t wa[52], wb[52];           // 104 regs of packed f16 weights
    #pragma unroll
    for (int j = 0; j < 52; ++j) {
        wa[j] = whp[(52 * s + j) * G_ + c0];
        wb[j] = whp[(52 * s + j) * G_ + c1];
    }
    float bhn_r = (c1 >= 2*H_) ? bhn[c1 - 2*H_] : 0.f;

    float hj = 0.f;
    if (tid < H_) {
        hj = first ? 0.f : hstate[b * H_ + tid];
        h_h[tid] = (_Float16)hj;
    }
    if (tid >= H_ && tid < 208) h_h[tid] = (_Float16)0.f;
    __syncthreads();

    const float* girow = gi + (size_t)b * TC * G_;
    _Float16* hsb = hs + (size_t)b * TC * H_;

    float g0 = 0.f, g1 = 0.f;
    if (s == 0) { g0 = girow[c0]; g1 = girow[c1]; }       // prefetch step 0
    for (int tc = 0; tc < TC; ++tc) {
        float g0n = 0.f, g1n = 0.f;                       // prefetch next step
        if (s == 0 && tc + 1 < TC) {
            g0n = girow[(size_t)(tc + 1) * G_ + c0];
            g1n = girow[(size_t)(tc + 1) * G_ + c1];
        }
        float a0 = 0.f, a1 = 0.f, a2 = 0.f, a3 = 0.f;
        float b0 = 0.f, b1 = 0.f, b2 = 0.f, b3 = 0.f;
        const float4* h4 = (const float4*)(h_h + 104 * s);   // 16B-aligned
        #pragma unroll
        for (int q = 0; q < 13; ++q) {
            float4 hv = h4[q];                   // 8 halves = 4 half2
            half2_t* hp = (half2_t*)&hv;
            a0 = fdot2_(hp[0], wa[4*q+0], a0);
            a1 = fdot2_(hp[1], wa[4*q+1], a1);
            a2 = fdot2_(hp[2], wa[4*q+2], a2);
            a3 = fdot2_(hp[3], wa[4*q+3], a3);
            b0 = fdot2_(hp[0], wb[4*q+0], b0);
            b1 = fdot2_(hp[1], wb[4*q+1], b1);
            b2 = fdot2_(hp[2], wb[4*q+2], b2);
            b3 = fdot2_(hp[3], wb[4*q+3], b3);
        }
        float accA = dpp_xor1_add((a0 + a1) + (a2 + a3));   // sum across lane pair
        float accB = dpp_xor1_add((b0 + b1) + (b2 + b3));
        if (s == 0) {
            A_lds[c0] = g0 + accA;               // c0 in [0,300): r or z cols
            if (c1 < 2*H_) {
                A_lds[c1] = g1 + accB;           // z cols 300..399
            } else {
                A_lds[c1] = g1;                  // n cols 400..599
                Hn_lds[c1 - 2*H_] = accB + bhn_r;
            }
        }
        LDS_BARRIER();                // LDS-visibility only: VMEM stays in flight
        if (tid < H_) {
            float r = sigmoid_(A_lds[tid]);
            float z = sigmoid_(A_lds[H_ + tid]);
            float n = tanh_(A_lds[2*H_ + tid] + r * Hn_lds[tid]);
            hj = n + z * (hj - n);
            h_h[tid] = (_Float16)hj;
            hsb[(size_t)tc * H_ + tid] = (_Float16)hj;   // fire-and-forget
        }
        LDS_BARRIER();
        g0 = g0n; g1 = g1n;
    }
    if (tid < H_) hstate[b * H_ + tid] = hj;
}

// ---------------- outproj body ----------------
__device__ __forceinline__
void out_body(const _Float16* __restrict__ hs, const float* __restrict__ Wo,
              const float* __restrict__ bo, float* __restrict__ out,
              int t0, int TC, int blk) {
    int r = blk * 640 + threadIdx.x;
    if (r >= B_ * TC) return;
    int b = r / TC, tc = r - b * TC;
    const float4* h4 = (const float4*)(hs + (size_t)r * H_);
    float acc = 0.f;
    #pragma unroll
    for (int q = 0; q < 25; ++q) {
        float4 v = h4[q];
        const _Float16* hp = (const _Float16*)&v;
        #pragma unroll
        for (int j = 0; j < 8; ++j)
            acc = fmaf((float)hp[j], Wo[q * 8 + j], acc);
    }
    out[(size_t)b * T_ + t0 + tc] = acc + bo[0];
}

// ---------------- Fused per-chunk kernel: scan(c) || gi(c+1) || outproj(c-1) ----------------
// Blocks 0..63: scan on 64 CUs. Blocks 64..64+TC-1: gi for next chunk on the
// other CUs. Remainder: outproj for previous chunk. The 84KB LDS pad makes any
// two blocks non-co-resident (2x84KB > 160KB LDS/CU), so gi/outproj blocks can
// never share a CU with a scan block and steal its VALU issue. Ordering between
// roles comes from stream-level kernel serialization + gi/hs ping-pong buffers.
__global__ __launch_bounds__(640, 1)
void fused_kernel(const float* __restrict__ x, const float* __restrict__ Wi,
                  const float* __restrict__ bi,
                  const float* __restrict__ gi_scan, float* __restrict__ gi_next,
                  const half2_t* __restrict__ whp, const float* __restrict__ bhn,
                  _Float16* __restrict__ hs_w, const _Float16* __restrict__ hs_r,
                  float* __restrict__ hstate,
                  const float* __restrict__ Wo, const float* __restrict__ bo,
                  float* __restrict__ out,
                  int c, int nc, int TC) {
    __shared__ __align__(16) char smem[SMEM_PAD];
    int blk = blockIdx.x;
    int gi_blocks = (B_ * TC) / 64;
    if (blk < 64) {
        scan_body(smem, gi_scan, whp, bhn, hs_w, hstate, TC, c == 0, blk);
    } else if (blk < 64 + gi_blocks) {
        if (c + 1 < nc)
            gi_body(smem, x, Wi, bi, gi_next, (c + 1) * TC, TC, blk - 64);
    } else {
        if (c >= 1)
            out_body(hs_r, Wo, bo, out, (c - 1) * TC, TC, blk - 64 - gi_blocks);
    }
}

// standalone gi for chunk 0 (full GPU, before the pipeline starts)
__global__ __launch_bounds__(640, 1)
void gi_kernel(const float* __restrict__ x, const float* __restrict__ Wi,
               const float* __restrict__ bi, float* __restrict__ gi,
               int t0, int TC) {
    __shared__ __align__(16) char smem[F_ * 68 * 4];
    gi_body(smem, x, Wi, bi, gi, t0, TC, blockIdx.x);
}

// standalone outproj for the last chunk
__global__ __launch_bounds__(256, 4)
void outproj_kernel(const _Float16* __restrict__ hs, const float* __restrict__ Wo,
                    const float* __restrict__ bo, float* __restrict__ out,
                    int t0, int TC) {
    int r = blockIdx.x * 256 + threadIdx.x;
    if (r >= B_ * TC) return;
    int b = r / TC, tc = r - b * TC;
    const float4* h4 = (const float4*)(hs + (size_t)r * H_);
    float acc = 0.f;
    #pragma unroll
    for (int q = 0; q < 25; ++q) {
        float4 v = h4[q];
        const _Float16* hp = (const _Float16*)&v;
        #pragma unroll
        for (int j = 0; j < 8; ++j)
            acc = fmaf((float)hp[j], Wo[q * 8 + j], acc);
    }
    out[(size_t)b * T_ + t0 + tc] = acc + bo[0];
}

extern "C" void kernel_launch(void* const* d_in, const int* in_sizes, int n_in,
                              void* d_out, int out_size, void* d_ws, size_t ws_size,
                              hipStream_t stream) {
    const float* x   = (const float*)d_in[0];
    const float* Wi  = (const float*)d_in[1];
    const float* bi  = (const float*)d_in[2];
    const float* Wh  = (const float*)d_in[3];
    const float* bhn = (const float*)d_in[4];
    const float* Wo  = (const float*)d_in[5];
    const float* bo  = (const float*)d_in[6];
    float* out = (float*)d_out;

    const size_t hstate_b = (size_t)B_ * H_ * sizeof(float);
    const size_t whp_b    = (size_t)KH_ * G_ * sizeof(half2_t);
    // ws layout (ping-pong): [gi0][gi1][hs0][hs1][hstate][whp]
    int TC = 512;
    while (TC > 64 &&
           2 * (size_t)B_ * TC * (G_ * 4 + H_ * 2) + hstate_b + whp_b > ws_size)
        TC >>= 1;
    int nc = T_ / TC;
    char* p = (char*)d_ws;
    const size_t gi_b = (size_t)B_ * TC * G_ * sizeof(float);
    const size_t hs_b = (size_t)B_ * TC * H_ * sizeof(_Float16);
    float*    gi0    = (float*)p;            p += gi_b;
    float*    gi1    = (float*)p;            p += gi_b;
    _Float16* hs0    = (_Float16*)p;         p += hs_b;
    _Float16* hs1    = (_Float16*)p;         p += hs_b;
    float*    hstate = (float*)p;            p += hstate_b;
    half2_t*  whp    = (half2_t*)p;

    prep_whp<<<dim3((KH_ * G_ + 255) / 256), dim3(256), 0, stream>>>(Wh, whp);

    int gi_blocks  = (B_ * TC) / 64;
    int out_blocks = (B_ * TC + 639) / 640;
    int grid = 64 + gi_blocks + out_blocks;

    // chunk 0 gi on the full GPU
    gi_kernel<<<dim3(gi_blocks), dim3(640), 0, stream>>>(x, Wi, bi, gi0, 0, TC);

    for (int c = 0; c < nc; ++c) {
        float*    gi_s = (c & 1) ? gi1 : gi0;          // scan reads chunk c
        float*    gi_w = (c & 1) ? gi0 : gi1;          // gi writes chunk c+1
        _Float16* hs_w = (c & 1) ? hs1 : hs0;          // scan writes chunk c
        _Float16* hs_r = (c & 1) ? hs0 : hs1;          // outproj reads chunk c-1
        fused_kernel<<<dim3(grid), dim3(640), 0, stream>>>(
            x, Wi, bi, gi_s, gi_w, whp, bhn, hs_w, hs_r, hstate,
            Wo, bo, out, c, nc, TC);
    }
    _Float16* hs_last = ((nc - 1) & 1) ? hs1 : hs0;
    outproj_kernel<<<dim3((B_ * TC + 255) / 256), dim3(256), 0, stream>>>(
        hs_last, Wo, bo, out, (nc - 1) * TC, TC);
}